// Round 1
// baseline (296.247 us; speedup 1.0000x reference)
//
#include <hip/hip_runtime.h>
#include <hip/hip_bf16.h>

// Problem: B=16, S=4096, H=1024
//   energy = tanh(x @ W^T + b); scores = softmax(energy, axis=S); out = sum_S scores*x
// GEMM view: M = B*S = 65536, N = H = 1024, K = H = 1024, both operands K-contiguous.
#define Bsz  16
#define Sdim 4096
#define Hdim 1024
#define Mtot (Bsz * Sdim)   // 65536
#define Kdim Hdim
#define Ndim Hdim
#define BM 128
#define BN 128
#define BK 32
#define MT (Mtot / BM)      // 512 m-tiles (each is one 128-row s-chunk of one batch)
#define NT (Ndim / BN)      // 8
#define NKT (Kdim / BK)     // 32 k-steps

typedef short s16x8 __attribute__((ext_vector_type(8)));
typedef float f32x4 __attribute__((ext_vector_type(4)));

__device__ __forceinline__ unsigned short f2bf(float f) {
  __hip_bfloat16 h = __float2bfloat16(f);
  unsigned short u;
  __builtin_memcpy(&u, &h, 2);
  return u;
}

__device__ __forceinline__ s16x8 cvt8(float4 u, float4 v) {
  s16x8 r;
  r[0] = (short)f2bf(u.x); r[1] = (short)f2bf(u.y);
  r[2] = (short)f2bf(u.z); r[3] = (short)f2bf(u.w);
  r[4] = (short)f2bf(v.x); r[5] = (short)f2bf(v.y);
  r[6] = (short)f2bf(v.z); r[7] = (short)f2bf(v.w);
  return r;
}

// ---- kernel 1: W fp32 [N][K] -> bf16 in workspace (2 MB) ----
__global__ __launch_bounds__(256) void wconv_kernel(const float* __restrict__ W,
                                                    unsigned short* __restrict__ Wb) {
  int i = blockIdx.x * 256 + threadIdx.x;  // float4 index, total N*K/4
  float4 v = reinterpret_cast<const float4*>(W)[i];
  ushort4 o;
  o.x = f2bf(v.x); o.y = f2bf(v.y); o.z = f2bf(v.z); o.w = f2bf(v.w);
  reinterpret_cast<ushort4*>(Wb)[i] = o;
}

// ---- kernel 2: fused GEMM + tanh + exp + per-chunk softmax partials ----
// Block: 256 threads = 4 waves in a 2x2 grid; each wave computes 64x64 via 4x4
// fragments of mfma_f32_16x16x32_bf16.
__global__ __launch_bounds__(256) void attn_main(
    const float* __restrict__ X,            // [Mtot][Kdim] fp32
    const unsigned short* __restrict__ Wb,  // [Ndim][Kdim] bf16
    const float* __restrict__ bias,         // [Ndim]
    float* __restrict__ lpart,              // [MT][Ndim]
    float* __restrict__ cpart) {            // [MT][Ndim]
  __shared__ unsigned short Al[BM * BK];    // 8 KB, [row][k] bf16
  __shared__ unsigned short Bl[BN * BK];    // 8 KB, [n][k]  bf16
  __shared__ float red[2][2][BN];           // [wm][{l,c}][col] 2 KB

  // XCD-chunked swizzle (bijective: 4096 % 8 == 0). HW round-robins blockIdx
  // across 8 XCDs; this gives each XCD a contiguous swz range -> the 8 nt
  // blocks sharing an A-panel co-reside on one XCD's L2.
  int bid = blockIdx.x;
  int swz = (bid & 7) * (MT * NT / 8) + (bid >> 3);
  int mt = swz >> 3;        // 0..511
  int nt = swz & 7;         // 0..7
  const int m0 = mt * BM;
  const int n0 = nt * BN;

  const int tid  = threadIdx.x;
  const int lane = tid & 63;
  const int wave = tid >> 6;
  const int wm = wave >> 1, wn = wave & 1;
  const int lr = lane & 15, lk = lane >> 4;

  f32x4 acc[4][4];
#pragma unroll
  for (int i = 0; i < 4; i++)
#pragma unroll
    for (int j = 0; j < 4; j++) acc[i][j] = (f32x4){0.f, 0.f, 0.f, 0.f};

  // staging: each thread owns 16 contiguous elements of one tile row
  const int srow_st = tid >> 1;            // 0..127
  const int scol_st = (tid & 1) * 16;      // 0 or 16 (elements)
  const float*          Ag = X  + (size_t)(m0 + srow_st) * Kdim + scol_st;
  const unsigned short* Bg = Wb + (size_t)(n0 + srow_st) * Kdim + scol_st;

  // prefetch k-tile 0
  float4 a0 = *(const float4*)(Ag + 0);
  float4 a1 = *(const float4*)(Ag + 4);
  float4 a2 = *(const float4*)(Ag + 8);
  float4 a3 = *(const float4*)(Ag + 12);
  s16x8  b0 = *(const s16x8*)(Bg + 0);
  s16x8  b1 = *(const s16x8*)(Bg + 8);

  for (int kt = 0; kt < NKT; ++kt) {
    __syncthreads();  // previous tile's LDS reads done
    *(s16x8*)&Al[srow_st * BK + scol_st]     = cvt8(a0, a1);
    *(s16x8*)&Al[srow_st * BK + scol_st + 8] = cvt8(a2, a3);
    *(s16x8*)&Bl[srow_st * BK + scol_st]     = b0;
    *(s16x8*)&Bl[srow_st * BK + scol_st + 8] = b1;
    __syncthreads();  // tile staged

    if (kt + 1 < NKT) {  // prefetch next k-tile under the MFMAs
      const float* ap = Ag + (kt + 1) * BK;
      a0 = *(const float4*)(ap);
      a1 = *(const float4*)(ap + 4);
      a2 = *(const float4*)(ap + 8);
      a3 = *(const float4*)(ap + 12);
      const unsigned short* bp = Bg + (kt + 1) * BK;
      b0 = *(const s16x8*)(bp);
      b1 = *(const s16x8*)(bp + 8);
    }

    s16x8 af[4], bfr[4];
#pragma unroll
    for (int mr = 0; mr < 4; mr++)
      af[mr] = *(const s16x8*)&Al[(wm * 64 + mr * 16 + lr) * BK + lk * 8];
#pragma unroll
    for (int nr = 0; nr < 4; nr++)
      bfr[nr] = *(const s16x8*)&Bl[(wn * 64 + nr * 16 + lr) * BK + lk * 8];
#pragma unroll
    for (int mr = 0; mr < 4; mr++)
#pragma unroll
      for (int nr = 0; nr < 4; nr++)
        acc[mr][nr] = __builtin_amdgcn_mfma_f32_16x16x32_bf16(af[mr], bfr[nr], acc[mr][nr], 0, 0, 0);
  }

  // ---- epilogue: e = tanh(acc + bias); partials l = sum exp(e), c = sum exp(e)*x
  // C/D layout: col = lane&15 (=lr), row = (lane>>4)*4 + reg (= lk*4 + r)
  // tanh is bounded -> softmax needs no max subtraction (exp(e) in [0.37, 2.72]).
  float lsum[4], csum[4];
#pragma unroll
  for (int nr = 0; nr < 4; nr++) {
    const int o = n0 + wn * 64 + nr * 16 + lr;
    const float bv = bias[o];
    float lacc = 0.f, cacc = 0.f;
#pragma unroll
    for (int mr = 0; mr < 4; mr++) {
      const int srow = m0 + wm * 64 + mr * 16 + lk * 4;
#pragma unroll
      for (int r = 0; r < 4; r++) {
        float e  = acc[mr][nr][r] + bv;
        float t  = __expf(2.f * e);                 // e bounded ~[-7,7]; no overflow
        float th = 1.f - __fdividef(2.f, t + 1.f);  // tanh(e)
        float sc = __expf(th);                      // softmax numerator
        float xv = X[(size_t)(srow + r) * Kdim + o];  // fp32 x for pooling
        lacc += sc;
        cacc += sc * xv;
      }
    }
    // sum the 4 lane-groups (rows) for this column
    lacc += __shfl_xor(lacc, 16); lacc += __shfl_xor(lacc, 32);
    cacc += __shfl_xor(cacc, 16); cacc += __shfl_xor(cacc, 32);
    lsum[nr] = lacc; csum[nr] = cacc;
  }

  if (lk == 0) {  // one copy per column per wave
#pragma unroll
    for (int nr = 0; nr < 4; nr++) {
      red[wm][0][wn * 64 + nr * 16 + lr] = lsum[nr];
      red[wm][1][wn * 64 + nr * 16 + lr] = csum[nr];
    }
  }
  __syncthreads();
  if (tid < BN) {  // combine the two row-halves, write chunk partials
    float L = red[0][0][tid] + red[1][0][tid];
    float C = red[0][1][tid] + red[1][1][tid];
    lpart[(size_t)mt * Ndim + n0 + tid] = L;
    cpart[(size_t)mt * Ndim + n0 + tid] = C;
  }
}

// ---- kernel 3: combine 32 s-chunks -> out[b][o] = sum(c)/sum(l) ----
__global__ __launch_bounds__(256) void finalize_kernel(const float* __restrict__ lpart,
                                                       const float* __restrict__ cpart,
                                                       float* __restrict__ out) {
  int i = blockIdx.x * 256 + threadIdx.x;  // 0..16383
  int b = i >> 10, o = i & 1023;
  float L = 0.f, C = 0.f;
#pragma unroll 4
  for (int sc = 0; sc < Sdim / BM; ++sc) {
    size_t idx = (size_t)(b * (Sdim / BM) + sc) * Ndim + o;
    L += lpart[idx];
    C += cpart[idx];
  }
  out[i] = C / L;
}

extern "C" void kernel_launch(void* const* d_in, const int* in_sizes, int n_in,
                              void* d_out, int out_size, void* d_ws, size_t ws_size,
                              hipStream_t stream) {
  const float* X    = (const float*)d_in[0];
  const float* W    = (const float*)d_in[1];
  const float* bias = (const float*)d_in[2];
  float* out = (float*)d_out;

  // ws layout: Wb bf16 [1024*1024] (2 MB) | lpart [512*1024] f32 (2 MB) | cpart (2 MB)
  unsigned short* Wb = (unsigned short*)d_ws;
  float* lpart = (float*)((char*)d_ws + (size_t)Ndim * Kdim * 2);
  float* cpart = lpart + (size_t)MT * Ndim;

  wconv_kernel<<<dim3(Ndim * Kdim / 1024), dim3(256), 0, stream>>>(W, Wb);
  attn_main<<<dim3(MT * NT), dim3(256), 0, stream>>>(X, Wb, bias, lpart, cpart);
  finalize_kernel<<<dim3(Bsz * Hdim / 256), dim3(256), 0, stream>>>(lpart, cpart, out);
}